// Round 6
// baseline (215.643 us; speedup 1.0000x reference)
//
#include <hip/hip_runtime.h>
#include <math.h>

typedef __fp16   h16x2 __attribute__((ext_vector_type(2)));   // cvt_pkrtz result type
typedef _Float16 f16x8 __attribute__((ext_vector_type(8)));
typedef __attribute__((ext_vector_type(4))) float f32x4;

#define KDIM 50176
#define NDIM 512
#define MDIM 512
#define BM 256
#define BN 128
#define BK 32

// fp16 two-plane split: h = rtz_fp16(a), l = rn_fp16((a - float(h)) * 2048)
// residual computed from the STORED h value, so any cvt denorm-flush self-heals.
__device__ __forceinline__ void split_pair(float a, float b, unsigned& hw, unsigned& lw) {
    h16x2 hp = __builtin_amdgcn_cvt_pkrtz(a, b);
    float ra = (a - (float)hp[0]) * 2048.0f;
    float rb = (b - (float)hp[1]) * 2048.0f;
    h16x2 lp;
    lp[0] = (__fp16)ra;   // RN
    lp[1] = (__fp16)rb;
    union { h16x2 v; unsigned u; } cu;
    cu.v = hp; hw = cu.u;
    cu.v = lp; lw = cu.u;
}

// ---- GEMM1: part[z] = A[:, kz] @ W1[kz, :]  via fp16 2-plane MFMA (3 products) ----
// A plane scales: Ah x1, Al x2^11. W pre-scaled by 64: Wh = w*2^6, Wl = w*2^17.
// C = acc0 * 2^-6 + acc1 * 2^-17.
// Round-4 geometry (256x128, 8 waves, dbuf BK32) + 4-cluster interleave with
// wave role-split: waves 0-3 stage W, waves 4-7 stage A; SIMD k hosts waves
// {k, k+4} = one of each role -> cross-wave MFMA/VALU overlap + setprio pays.
__global__ __launch_bounds__(512, 2) void gemm1_mfma(
    const float* __restrict__ A,      // [512][50176]
    const float* __restrict__ W,      // [50176][512]
    float* __restrict__ part,         // [S][512][512]
    int steps)
{
    __shared__ unsigned short Ahs[2][256][40];   // 40-half rows: 16B-aligned b128 frag reads
    __shared__ unsigned short Als[2][256][40];
    __shared__ unsigned short Bhs[2][128][40];
    __shared__ unsigned short Bls[2][128][40];   // 122880 B total

    const int t = threadIdx.x;
    const int bm = blockIdx.x, bn = blockIdx.y, z = blockIdx.z;
    const int kbase = z * steps * BK;

    const int lane = t & 63, wave = t >> 6;
    const int wm = wave >> 1, wn2 = wave & 1;    // 4x2 wave grid, 64x64 per wave
    const int l15 = lane & 15, lh = lane >> 4;

    const bool isW = (t < 256);                  // waves 0-3: W-stagers; 4-7: A-stagers
    const int u = isW ? t : (t - 256);
    const int wkb = u & 7, wn0 = (u >> 3) * 4;   // W micro: 4k x 4n
    const int achunk = u & 7, arow0 = u >> 3;    // A: rows arow0+32j, one float4 chunk

    f32x4 acc0[4][4], acc1[4][4];
#pragma unroll
    for (int i = 0; i < 4; ++i)
#pragma unroll
        for (int j = 0; j < 4; ++j) { acc0[i][j] = (f32x4)0.f; acc1[i][j] = (f32x4)0.f; }

    float4 reg[8];
    auto gload = [&](int s) {
        const int k0 = kbase + s * BK;
        if (isW) {
            const float* Wb = W + (size_t)k0 * NDIM + bn * BN + wn0;
#pragma unroll
            for (int i = 0; i < 4; ++i)
                reg[i] = *(const float4*)(Wb + (size_t)(wkb * 4 + i) * NDIM);
        } else {
            const float* Ab = A + (size_t)(bm * BM) * KDIM + k0 + achunk * 4;
#pragma unroll
            for (int j = 0; j < 8; ++j)
                reg[j] = *(const float4*)(Ab + (size_t)(arow0 + 32 * j) * KDIM);
        }
    };

    // stage one A row-chunk j (rows arow0+32j)
    auto stageA = [&](int buf, int j) {
        unsigned h01, l01, h23, l23;
        split_pair(reg[j].x, reg[j].y, h01, l01);
        split_pair(reg[j].z, reg[j].w, h23, l23);
        *(uint2*)&Ahs[buf][arow0 + 32 * j][achunk * 4] = make_uint2(h01, h23);
        *(uint2*)&Als[buf][arow0 + 32 * j][achunk * 4] = make_uint2(l01, l23);
    };
    // stage one W n-row j (needs component j of all 4 loads)
    auto stageW = [&](int buf, int j) {
        unsigned h01, l01, h23, l23;
        split_pair(((const float*)&reg[0])[j] * 64.0f, ((const float*)&reg[1])[j] * 64.0f, h01, l01);
        split_pair(((const float*)&reg[2])[j] * 64.0f, ((const float*)&reg[3])[j] * 64.0f, h23, l23);
        *(uint2*)&Bhs[buf][wn0 + j][wkb * 4] = make_uint2(h01, h23);
        *(uint2*)&Bls[buf][wn0 + j][wkb * 4] = make_uint2(l01, l23);
    };
    auto full_stage = [&](int buf) {
        if (isW) {
#pragma unroll
            for (int j = 0; j < 4; ++j) stageW(buf, j);
        } else {
#pragma unroll
            for (int j = 0; j < 8; ++j) stageA(buf, j);
        }
    };

    gload(0);
    full_stage(0);
    __syncthreads();
    int cur = 0;
    for (int s = 0; s < steps; ++s) {
        const bool pf = (s + 1 < steps);
        if (pf) gload(s + 1);                    // issue next-tile loads early

        // a-frags upfront (held across clusters)
        f16x8 ah[4], al[4];
#pragma unroll
        for (int mf = 0; mf < 4; ++mf) {
            ah[mf] = *(const f16x8*)&Ahs[cur][wm * 64 + mf * 16 + l15][lh * 8];
            al[mf] = *(const f16x8*)&Als[cur][wm * 64 + mf * 16 + l15][lh * 8];
        }

        // 4 clusters: {b-frags, 12 MFMA, stage chunk for next buffer}
#pragma unroll
        for (int nf = 0; nf < 4; ++nf) {
            f16x8 bh = *(const f16x8*)&Bhs[cur][wn2 * 64 + nf * 16 + l15][lh * 8];
            f16x8 bl = *(const f16x8*)&Bls[cur][wn2 * 64 + nf * 16 + l15][lh * 8];
            __builtin_amdgcn_s_setprio(1);
#pragma unroll
            for (int mf = 0; mf < 4; ++mf) {
                acc0[mf][nf] = __builtin_amdgcn_mfma_f32_16x16x32_f16(ah[mf], bh, acc0[mf][nf], 0, 0, 0);
                acc1[mf][nf] = __builtin_amdgcn_mfma_f32_16x16x32_f16(ah[mf], bl, acc1[mf][nf], 0, 0, 0);
                acc1[mf][nf] = __builtin_amdgcn_mfma_f32_16x16x32_f16(al[mf], bh, acc1[mf][nf], 0, 0, 0);
            }
            __builtin_amdgcn_s_setprio(0);
            if (pf) {
                if (isW) {
                    if (nf == 0) {               // one vmcnt drain, then pure MFMA clusters
#pragma unroll
                        for (int j = 0; j < 4; ++j) stageW(cur ^ 1, j);
                    }
                } else {
                    stageA(cur ^ 1, 2 * nf);
                    stageA(cur ^ 1, 2 * nf + 1);
                }
            }
        }
        __syncthreads();
        cur ^= 1;
    }

    const float c0 = 1.0f / 64.0f;
    const float c1 = 1.0f / 131072.0f;
    float* Cp = part + (size_t)z * (MDIM * NDIM);
    const int row0 = bm * BM + wm * 64;
    const int col0 = bn * BN + wn2 * 64;
#pragma unroll
    for (int mf = 0; mf < 4; ++mf)
#pragma unroll
        for (int nf = 0; nf < 4; ++nf) {
            const int r0 = row0 + mf * 16 + lh * 4;
            const int c = col0 + nf * 16 + l15;
#pragma unroll
            for (int r = 0; r < 4; ++r)
                Cp[(size_t)(r0 + r) * NDIM + c] = acc0[mf][nf][r] * c0 + acc1[mf][nf][r] * c1;
        }
}

// ---------------- reduce partials + bias + relu -> h1 (float4) ----------------
__global__ __launch_bounds__(256) void reduce_bias_relu(
    const float4* __restrict__ part, const float* __restrict__ b1,
    float4* __restrict__ h1, int S)
{
    int i = blockIdx.x * 256 + threadIdx.x;      // 0..65535 float4s
    float4 s = make_float4(0.f, 0.f, 0.f, 0.f);
    for (int z = 0; z < S; ++z) {
        float4 v = part[(size_t)z * 65536 + i];
        s.x += v.x; s.y += v.y; s.z += v.z; s.w += v.w;
    }
    int nb = (i & 127) * 4;
    s.x = fmaxf(s.x + b1[nb + 0], 0.f);
    s.y = fmaxf(s.y + b1[nb + 1], 0.f);
    s.z = fmaxf(s.z + b1[nb + 2], 0.f);
    s.w = fmaxf(s.w + b1[nb + 3], 0.f);
    h1[i] = s;
}

// ---------------- layer 2: h2 = relu(h1 @ W2 + b2) ----------------
__global__ __launch_bounds__(256) void gemm2_k(
    const float* __restrict__ h1, const float* __restrict__ W2,
    const float* __restrict__ b2, float* __restrict__ h2)
{
    int g = blockIdx.x * 256 + threadIdx.x;     // 0..131071
    int m = g >> 8, n = g & 255;
    const float* a = h1 + (size_t)m * 512;
    float sum = 0.f;
#pragma unroll 8
    for (int k = 0; k < 512; ++k) sum = fmaf(a[k], W2[(size_t)k * 256 + n], sum);
    sum += b2[n];
    h2[g] = fmaxf(sum, 0.f);
}

// ---------------- layer 3: pred = sigmoid(h2 @ W3 + b3) ----------------
__global__ __launch_bounds__(256) void gemm3_sig(
    const float* __restrict__ h2, const float* __restrict__ W3,
    const float* __restrict__ b3, float* __restrict__ pred)
{
    int g = blockIdx.x * 256 + threadIdx.x;     // 0..8191
    int m = g >> 4, j = g & 15;
    const float* a = h2 + (size_t)m * 256;
    float sum = 0.f;
#pragma unroll 8
    for (int k = 0; k < 256; ++k) sum = fmaf(a[k], W3[(size_t)k * 16 + j], sum);
    sum += b3[j];
    pred[g] = 1.f / (1.f + expf(-sum));
}

// ---------------- patch gathers ----------------
__device__ __forceinline__ int clip_coord(float v) {
    int c = (int)(v * 224.0f);
    if (c >= 219) c = 200;
    if (c <= 5)   c = 8;
    return c;
}

__global__ void patches_k(
    const float* __restrict__ pm, const float* __restrict__ gt,
    const float* __restrict__ pred, float* __restrict__ out)
{
    const int b = blockIdx.x;
    const int t = threadIdx.x;          // 0..287
    const int lm = t / 36, cell = t % 36;
    const int dx = cell / 6 - 3, dy = cell % 6 - 3;
    const float* pmb = pm + (size_t)b * 50176;
    {
        int cx = clip_coord(gt[b * 16 + lm * 2 + 0]);
        int cy = clip_coord(gt[b * 16 + lm * 2 + 1]);
        out[8192 + b * 288 + t] = pmb[(cx + dx) * 224 + (cy + dy)];
    }
    {
        int cx = clip_coord(pred[b * 16 + lm * 2 + 0]);
        int cy = clip_coord(pred[b * 16 + lm * 2 + 1]);
        out[8192 + 147456 + b * 288 + t] = pmb[(cx + dx) * 224 + (cy + dy)];
    }
}

extern "C" void kernel_launch(void* const* d_in, const int* in_sizes, int n_in,
                              void* d_out, int out_size, void* d_ws, size_t ws_size,
                              hipStream_t stream)
{
    const float* pred_map = (const float*)d_in[0];
    const float* gt       = (const float*)d_in[1];
    const float* W1       = (const float*)d_in[2];
    const float* b1       = (const float*)d_in[3];
    const float* W2       = (const float*)d_in[4];
    const float* b2       = (const float*)d_in[5];
    const float* W3       = (const float*)d_in[6];
    const float* b3       = (const float*)d_in[7];
    float* out = (float*)d_out;

    float* h1   = (float*)d_ws;          // 262144 floats
    float* h2   = h1 + 262144;           // 131072 floats
    float* part = h2 + 131072;           // S * 262144 floats

    // largest split-K factor (dividing 1568) that fits the workspace
    static const int cand[] = {32, 16, 8, 4, 2, 1};
    int S = 1;
    for (int i = 0; i < 6; ++i) {
        size_t need = (size_t)(393216 + (size_t)cand[i] * 262144) * sizeof(float);
        if (need <= ws_size) { S = cand[i]; break; }
    }
    const int steps = 1568 / S;

    hipLaunchKernelGGL(gemm1_mfma, dim3(2, 4, S), dim3(512), 0, stream,
                       pred_map, W1, part, steps);
    hipLaunchKernelGGL(reduce_bias_relu, dim3(256), dim3(256), 0, stream,
                       (const float4*)part, b1, (float4*)h1, S);
    hipLaunchKernelGGL(gemm2_k, dim3(131072 / 256), dim3(256), 0, stream, h1, W2, b2, h2);
    hipLaunchKernelGGL(gemm3_sig, dim3(8192 / 256), dim3(256), 0, stream, h2, W3, b3, out);
    hipLaunchKernelGGL(patches_k, dim3(512), dim3(288), 0, stream, pred_map, gt, out, out);
}

// Round 7
// 152.068 us; speedup vs baseline: 1.4181x; 1.4181x over previous
//
#include <hip/hip_runtime.h>
#include <math.h>

typedef __fp16   h16x2 __attribute__((ext_vector_type(2)));   // cvt_pkrtz result type
typedef _Float16 f16x8 __attribute__((ext_vector_type(8)));
typedef __attribute__((ext_vector_type(4))) float f32x4;

#define KDIM 50176
#define NDIM 512
#define MDIM 512
#define BM 256
#define BN 128
#define BK 32

// fp16 two-plane split: h = rtz_fp16(a), l = rtz_fp16((a - float(h)) * 2048)
// residual computed from the STORED h value, so any cvt denorm-flush self-heals.
__device__ __forceinline__ void split_pair(float a, float b, unsigned& hw, unsigned& lw) {
    h16x2 hp = __builtin_amdgcn_cvt_pkrtz(a, b);
    float ra = (a - (float)hp[0]) * 2048.0f;
    float rb = (b - (float)hp[1]) * 2048.0f;
    h16x2 lp = __builtin_amdgcn_cvt_pkrtz(ra, rb);
    union { h16x2 v; unsigned u; } cu;
    cu.v = hp; hw = cu.u;
    cu.v = lp; lw = cu.u;
}

// ---- GEMM1: part[z] = A[:, kz] @ W1[kz, :]  via fp16 2-plane MFMA (3 products) ----
// A plane scales: Ah x1, Al x2^11. W pre-scaled by 64: Wh = w*2^6, Wl = w*2^17.
// C = acc0 * 2^-6 + acc1 * 2^-17.
// Round-4 geometry (256x128, 8 waves, dbuf BK32, 1 barrier/step) with phase-spread:
// phase nf: {read b-frags(nf+1) one-ahead | 12 MFMA | stage chunk nf -> buf^1}.
// gload regs consumed 2-per-phase in issue order -> compiler emits counted vmcnt.
__global__ __launch_bounds__(512, 2) void gemm1_mfma(
    const float* __restrict__ A,      // [512][50176]
    const float* __restrict__ W,      // [50176][512]
    float* __restrict__ part,         // [S][512][512]
    int steps, int S)
{
    __shared__ unsigned short Ahs[2][256][40];   // 40-half rows: 16B-aligned b128 frag reads
    __shared__ unsigned short Als[2][256][40];
    __shared__ unsigned short Bhs[2][128][40];
    __shared__ unsigned short Bls[2][128][40];   // 122880 B total

    const int t = threadIdx.x;

    // z-group XCD swizzle: the 8 blocks sharing a K-slice (2bm x 4bn) land on
    // one XCD (hw xcd = blk%8) so A/W tile re-reads hit that XCD's L2.
    const int nwg = 8 * S;
    int l = blockIdx.x;
    if ((nwg & 7) == 0) l = (l & 7) * (nwg >> 3) + (l >> 3);
    const int z = l >> 3, bm = l & 1, bn = (l >> 1) & 3;
    const int kbase = z * steps * BK;

    const int lane = t & 63, wave = t >> 6;
    const int wm = wave >> 1, wn2 = wave & 1;    // 4x2 wave grid, 64x64 per wave
    const int l15 = lane & 15, lh = lane >> 4;

    const bool isW = (t < 256);                  // waves 0-3 stage W; 4-7 stage A
    const int u = isW ? t : (t - 256);
    const int wkb = u & 7, wn0 = (u >> 3) * 4;   // W micro: 4k x 4n
    const int achunk = u & 7, arow0 = u >> 3;    // A: rows arow0+32j, one float4 chunk

    f32x4 acc0[4][4], acc1[4][4];
#pragma unroll
    for (int i = 0; i < 4; ++i)
#pragma unroll
        for (int j = 0; j < 4; ++j) { acc0[i][j] = (f32x4)0.f; acc1[i][j] = (f32x4)0.f; }

    float4 reg[8];
    auto gload = [&](int s) {
        const int k0 = kbase + s * BK;
        if (isW) {
            const float* Wb = W + (size_t)k0 * NDIM + bn * BN + wn0;
#pragma unroll
            for (int i = 0; i < 4; ++i)
                reg[i] = *(const float4*)(Wb + (size_t)(wkb * 4 + i) * NDIM);
        } else {
            const float* Ab = A + (size_t)(bm * BM) * KDIM + k0 + achunk * 4;
#pragma unroll
            for (int j = 0; j < 8; ++j)
                reg[j] = *(const float4*)(Ab + (size_t)(arow0 + 32 * j) * KDIM);
        }
    };

    // stage one A row-chunk j (rows arow0+32j) — consumes reg[j]
    auto stageA = [&](int buf, int j) {
        unsigned h01, l01, h23, l23;
        split_pair(reg[j].x, reg[j].y, h01, l01);
        split_pair(reg[j].z, reg[j].w, h23, l23);
        *(uint2*)&Ahs[buf][arow0 + 32 * j][achunk * 4] = make_uint2(h01, h23);
        *(uint2*)&Als[buf][arow0 + 32 * j][achunk * 4] = make_uint2(l01, l23);
    };
    // stage one W n-row j — consumes component j of reg[0..3]
    auto stageW = [&](int buf, int j) {
        unsigned h01, l01, h23, l23;
        split_pair(((const float*)&reg[0])[j] * 64.0f, ((const float*)&reg[1])[j] * 64.0f, h01, l01);
        split_pair(((const float*)&reg[2])[j] * 64.0f, ((const float*)&reg[3])[j] * 64.0f, h23, l23);
        *(uint2*)&Bhs[buf][wn0 + j][wkb * 4] = make_uint2(h01, h23);
        *(uint2*)&Bls[buf][wn0 + j][wkb * 4] = make_uint2(l01, l23);
    };
    auto full_stage = [&](int buf) {
        if (isW) {
#pragma unroll
            for (int j = 0; j < 4; ++j) stageW(buf, j);
        } else {
#pragma unroll
            for (int j = 0; j < 8; ++j) stageA(buf, j);
        }
    };

    gload(0);
    full_stage(0);
    __syncthreads();
    int cur = 0;
    for (int s = 0; s < steps; ++s) {
        const bool pf = (s + 1 < steps);
        if (pf) gload(s + 1);                    // issue next-tile loads first

        // a-frags + b-frags(0) upfront
        f16x8 ah[4], al[4];
#pragma unroll
        for (int mf = 0; mf < 4; ++mf) {
            ah[mf] = *(const f16x8*)&Ahs[cur][wm * 64 + mf * 16 + l15][lh * 8];
            al[mf] = *(const f16x8*)&Als[cur][wm * 64 + mf * 16 + l15][lh * 8];
        }
        f16x8 bh[2], bl[2];
        bh[0] = *(const f16x8*)&Bhs[cur][wn2 * 64 + l15][lh * 8];
        bl[0] = *(const f16x8*)&Bls[cur][wn2 * 64 + l15][lh * 8];

#pragma unroll
        for (int nf = 0; nf < 4; ++nf) {
            const int c = nf & 1, n = c ^ 1;
            if (nf < 3) {                        // read NEXT phase's b-frags first
                bh[n] = *(const f16x8*)&Bhs[cur][wn2 * 64 + (nf + 1) * 16 + l15][lh * 8];
                bl[n] = *(const f16x8*)&Bls[cur][wn2 * 64 + (nf + 1) * 16 + l15][lh * 8];
            }
            __builtin_amdgcn_s_setprio(1);
#pragma unroll
            for (int mf = 0; mf < 4; ++mf) {
                acc0[mf][nf] = __builtin_amdgcn_mfma_f32_16x16x32_f16(ah[mf], bh[c], acc0[mf][nf], 0, 0, 0);
                acc1[mf][nf] = __builtin_amdgcn_mfma_f32_16x16x32_f16(ah[mf], bl[c], acc1[mf][nf], 0, 0, 0);
                acc1[mf][nf] = __builtin_amdgcn_mfma_f32_16x16x32_f16(al[mf], bh[c], acc1[mf][nf], 0, 0, 0);
            }
            __builtin_amdgcn_s_setprio(0);
            if (pf) {                            // stage chunk nf for next step
                if (isW) {
                    stageW(cur ^ 1, nf);         // consumes reg[0..3][nf]
                } else {
                    stageA(cur ^ 1, 2 * nf);     // consumes reg[2nf], reg[2nf+1]
                    stageA(cur ^ 1, 2 * nf + 1);
                }
            }
        }
        __syncthreads();
        cur ^= 1;
    }

    const float c0 = 1.0f / 64.0f;
    const float c1 = 1.0f / 131072.0f;
    float* Cp = part + (size_t)z * (MDIM * NDIM);
    const int row0 = bm * BM + wm * 64;
    const int col0 = bn * BN + wn2 * 64;
#pragma unroll
    for (int mf = 0; mf < 4; ++mf)
#pragma unroll
        for (int nf = 0; nf < 4; ++nf) {
            const int r0 = row0 + mf * 16 + lh * 4;
            const int c = col0 + nf * 16 + l15;
#pragma unroll
            for (int r = 0; r < 4; ++r)
                Cp[(size_t)(r0 + r) * NDIM + c] = acc0[mf][nf][r] * c0 + acc1[mf][nf][r] * c1;
        }
}

// ---------------- reduce partials + bias + relu -> h1 (float4) ----------------
__global__ __launch_bounds__(256) void reduce_bias_relu(
    const float4* __restrict__ part, const float* __restrict__ b1,
    float4* __restrict__ h1, int S)
{
    int i = blockIdx.x * 256 + threadIdx.x;      // 0..65535 float4s
    float4 s = make_float4(0.f, 0.f, 0.f, 0.f);
    for (int z = 0; z < S; ++z) {
        float4 v = part[(size_t)z * 65536 + i];
        s.x += v.x; s.y += v.y; s.z += v.z; s.w += v.w;
    }
    int nb = (i & 127) * 4;
    s.x = fmaxf(s.x + b1[nb + 0], 0.f);
    s.y = fmaxf(s.y + b1[nb + 1], 0.f);
    s.z = fmaxf(s.z + b1[nb + 2], 0.f);
    s.w = fmaxf(s.w + b1[nb + 3], 0.f);
    h1[i] = s;
}

// ---------------- layer 2: h2 = relu(h1 @ W2 + b2) ----------------
__global__ __launch_bounds__(256) void gemm2_k(
    const float* __restrict__ h1, const float* __restrict__ W2,
    const float* __restrict__ b2, float* __restrict__ h2)
{
    int g = blockIdx.x * 256 + threadIdx.x;     // 0..131071
    int m = g >> 8, n = g & 255;
    const float* a = h1 + (size_t)m * 512;
    float sum = 0.f;
#pragma unroll 8
    for (int k = 0; k < 512; ++k) sum = fmaf(a[k], W2[(size_t)k * 256 + n], sum);
    sum += b2[n];
    h2[g] = fmaxf(sum, 0.f);
}

// ---------------- layer 3: pred = sigmoid(h2 @ W3 + b3) ----------------
__global__ __launch_bounds__(256) void gemm3_sig(
    const float* __restrict__ h2, const float* __restrict__ W3,
    const float* __restrict__ b3, float* __restrict__ pred)
{
    int g = blockIdx.x * 256 + threadIdx.x;     // 0..8191
    int m = g >> 4, j = g & 15;
    const float* a = h2 + (size_t)m * 256;
    float sum = 0.f;
#pragma unroll 8
    for (int k = 0; k < 256; ++k) sum = fmaf(a[k], W3[(size_t)k * 16 + j], sum);
    sum += b3[j];
    pred[g] = 1.f / (1.f + expf(-sum));
}

// ---------------- patch gathers ----------------
__device__ __forceinline__ int clip_coord(float v) {
    int c = (int)(v * 224.0f);
    if (c >= 219) c = 200;
    if (c <= 5)   c = 8;
    return c;
}

__global__ void patches_k(
    const float* __restrict__ pm, const float* __restrict__ gt,
    const float* __restrict__ pred, float* __restrict__ out)
{
    const int b = blockIdx.x;
    const int t = threadIdx.x;          // 0..287
    const int lm = t / 36, cell = t % 36;
    const int dx = cell / 6 - 3, dy = cell % 6 - 3;
    const float* pmb = pm + (size_t)b * 50176;
    {
        int cx = clip_coord(gt[b * 16 + lm * 2 + 0]);
        int cy = clip_coord(gt[b * 16 + lm * 2 + 1]);
        out[8192 + b * 288 + t] = pmb[(cx + dx) * 224 + (cy + dy)];
    }
    {
        int cx = clip_coord(pred[b * 16 + lm * 2 + 0]);
        int cy = clip_coord(pred[b * 16 + lm * 2 + 1]);
        out[8192 + 147456 + b * 288 + t] = pmb[(cx + dx) * 224 + (cy + dy)];
    }
}

extern "C" void kernel_launch(void* const* d_in, const int* in_sizes, int n_in,
                              void* d_out, int out_size, void* d_ws, size_t ws_size,
                              hipStream_t stream)
{
    const float* pred_map = (const float*)d_in[0];
    const float* gt       = (const float*)d_in[1];
    const float* W1       = (const float*)d_in[2];
    const float* b1       = (const float*)d_in[3];
    const float* W2       = (const float*)d_in[4];
    const float* b2       = (const float*)d_in[5];
    const float* W3       = (const float*)d_in[6];
    const float* b3       = (const float*)d_in[7];
    float* out = (float*)d_out;

    float* h1   = (float*)d_ws;          // 262144 floats
    float* h2   = h1 + 262144;           // 131072 floats
    float* part = h2 + 131072;           // S * 262144 floats

    // largest split-K factor (dividing 1568) that fits the workspace
    static const int cand[] = {32, 16, 8, 4, 2, 1};
    int S = 1;
    for (int i = 0; i < 6; ++i) {
        size_t need = (size_t)(393216 + (size_t)cand[i] * 262144) * sizeof(float);
        if (need <= ws_size) { S = cand[i]; break; }
    }
    const int steps = 1568 / S;

    hipLaunchKernelGGL(gemm1_mfma, dim3(8 * S), dim3(512), 0, stream,
                       pred_map, W1, part, steps, S);
    hipLaunchKernelGGL(reduce_bias_relu, dim3(256), dim3(256), 0, stream,
                       (const float4*)part, b1, (float4*)h1, S);
    hipLaunchKernelGGL(gemm2_k, dim3(131072 / 256), dim3(256), 0, stream, h1, W2, b2, h2);
    hipLaunchKernelGGL(gemm3_sig, dim3(8192 / 256), dim3(256), 0, stream, h2, W3, b3, out);
    hipLaunchKernelGGL(patches_k, dim3(512), dim3(288), 0, stream, pred_map, gt, out, out);
}